// Round 1
// baseline (156.920 us; speedup 1.0000x reference)
//
#include <hip/hip_runtime.h>
#include <cstddef>

#define Bsz 256
#define Dsz 512
#define Gsz 64
#define Nsz 8
#define Ksz 512
#define DDsz 1024  // D*2 interleaved (mu,sig)

// ws float offsets (total ~2.1 MB)
#define WS_Z     0         // [B][DD] interleaved mu/sig  (262144)
#define WS_DFLAT 262144    // [K][B] d_kb                 (131072)
#define WS_SOFTS 393216    // [B][G][N]                   (131072)
#define WS_PS    524288    // [B][G]                      (16384)
#define WS_BNORM 540672    // [B]
#define WS_CNORM 540928    // [K]

// out float offsets
#define OUT_QMU  0
#define OUT_QSIG 33554432
#define OUT_DBG  67108864
#define OUT_DIST 67125248

// ---------- K1a: sig = exp(logsig), build interleaved z[b][2d+e], bnorm ----------
__global__ __launch_bounds__(256) void k_prep_b(const float* __restrict__ mu,
                                                const float* __restrict__ ls,
                                                float* __restrict__ ws) {
  int b = blockIdx.x, t = threadIdx.x;
  float part = 0.f;
  float* z = ws + WS_Z + (size_t)b * DDsz;
  for (int d = t; d < Dsz; d += 256) {
    float m = mu[b * Dsz + d];
    float s = expf(ls[b * Dsz + d]);
    z[2 * d] = m;
    z[2 * d + 1] = s;
    part += m * m + s * s;
  }
  __shared__ float red[256];
  red[t] = part;
  __syncthreads();
  for (int off = 128; off > 0; off >>= 1) {
    if (t < off) red[t] += red[t + off];
    __syncthreads();
  }
  if (t == 0) ws[WS_BNORM + b] = red[0];
}

// ---------- K1b: cnorm[k] = sum over interleaved row of squares ----------
__global__ __launch_bounds__(256) void k_prep_c(const float* __restrict__ on,
                                                float* __restrict__ ws) {
  int k = blockIdx.x, t = threadIdx.x;
  float4 v = *(const float4*)(on + (size_t)k * DDsz + t * 4);
  float part = v.x * v.x + v.y * v.y + v.z * v.z + v.w * v.w;
  __shared__ float red[256];
  red[t] = part;
  __syncthreads();
  for (int off = 128; off > 0; off >>= 1) {
    if (t < off) red[t] += red[t + off];
    __syncthreads();
  }
  if (t == 0) ws[WS_CNORM + k] = red[0];
}

// ---------- K2: d_kb[k][b] = cnorm + bnorm - 2*dot1024(on[k], z[b]) ----------
__global__ __launch_bounds__(256) void k_dkb(const float* __restrict__ on,
                                             float* __restrict__ ws) {
  __shared__ float A[64][36];   // [c][k-local]
  __shared__ float Bs[64][36];  // [c][b-local]
  int kt = blockIdx.x >> 3, bt = blockIdx.x & 7;
  int k0 = kt * 32, b0 = bt * 32;
  int t = threadIdx.x, tx = t & 15, ty = t >> 4;
  const float* z = ws + WS_Z;
  float a00 = 0.f, a01 = 0.f, a10 = 0.f, a11 = 0.f;
  for (int c0 = 0; c0 < DDsz; c0 += 64) {
#pragma unroll
    for (int rep = 0; rep < 2; ++rep) {
      int tt = t + rep * 256;
      int r = tt >> 4;          // 0..31 row within tile
      int c4 = (tt & 15) << 2;  // 0..60
      float4 v = *(const float4*)(on + (size_t)(k0 + r) * DDsz + c0 + c4);
      A[c4 + 0][r] = v.x; A[c4 + 1][r] = v.y; A[c4 + 2][r] = v.z; A[c4 + 3][r] = v.w;
      float4 w = *(const float4*)(z + (size_t)(b0 + r) * DDsz + c0 + c4);
      Bs[c4 + 0][r] = w.x; Bs[c4 + 1][r] = w.y; Bs[c4 + 2][r] = w.z; Bs[c4 + 3][r] = w.w;
    }
    __syncthreads();
#pragma unroll 8
    for (int c = 0; c < 64; ++c) {
      float x0 = A[c][ty * 2], x1 = A[c][ty * 2 + 1];
      float y0 = Bs[c][tx * 2], y1 = Bs[c][tx * 2 + 1];
      a00 += x0 * y0; a01 += x0 * y1; a10 += x1 * y0; a11 += x1 * y1;
    }
    __syncthreads();
  }
  int kk = k0 + ty * 2, bb = b0 + tx * 2;
  float cn0 = ws[WS_CNORM + kk], cn1 = ws[WS_CNORM + kk + 1];
  float bn0 = ws[WS_BNORM + bb], bn1 = ws[WS_BNORM + bb + 1];
  float* df = ws + WS_DFLAT;
  df[kk * Bsz + bb]           = cn0 + bn0 - 2.f * a00;
  df[kk * Bsz + bb + 1]       = cn0 + bn1 - 2.f * a01;
  df[(kk + 1) * Bsz + bb]     = cn1 + bn0 - 2.f * a10;
  df[(kk + 1) * Bsz + bb + 1] = cn1 + bn1 - 2.f * a11;
}

// ---------- K3: per-(b,g) softmax over 8 scrambled entries ----------
__global__ __launch_bounds__(256) void k_gsm(float* __restrict__ ws,
                                             float* __restrict__ out) {
  int gid = blockIdx.x * 256 + threadIdx.x;  // 0..16383  (= b*64+g)
  int b = gid >> 6, g = gid & 63;
  const float* df = ws + WS_DFLAT;
  int k = 2 * b + (g >> 5);
  int col = (g & 31) << 3;
  const float* p = df + k * Bsz + col;
  float4 v0 = *(const float4*)p;
  float4 v1 = *(const float4*)(p + 4);
  float d[8] = {v0.x, v0.y, v0.z, v0.w, v1.x, v1.y, v1.z, v1.w};
  float m = d[0];
#pragma unroll
  for (int n = 1; n < 8; ++n) m = fminf(m, d[n]);
  float w[8], s = 0.f, wd = 0.f;
#pragma unroll
  for (int n = 0; n < 8; ++n) {
    w[n] = expf(m - d[n]);
    s += w[n];
    wd += w[n] * d[n];
  }
  float inv = 1.f / s;
  float* so = ws + WS_SOFTS + (size_t)gid * 8;
  float4 o0 = make_float4(w[0] * inv, w[1] * inv, w[2] * inv, w[3] * inv);
  float4 o1 = make_float4(w[4] * inv, w[5] * inv, w[6] * inv, w[7] * inv);
  *(float4*)so = o0;
  *(float4*)(so + 4) = o1;
  out[OUT_DBG + gid] = wd * inv;
}

// ---------- K4: ps = softmax over batch axis (per group) ----------
__global__ __launch_bounds__(256) void k_ps(const float* __restrict__ out,
                                            float* __restrict__ ws) {
  int g = blockIdx.x, t = threadIdx.x;  // t = b
  float v = out[OUT_DBG + t * Gsz + g];
  __shared__ float red[256];
  red[t] = v;
  __syncthreads();
  for (int off = 128; off > 0; off >>= 1) {
    if (t < off) red[t] = fminf(red[t], red[t + off]);
    __syncthreads();
  }
  float m = red[0];
  __syncthreads();
  float w = expf(m - v);
  red[t] = w;
  __syncthreads();
  for (int off = 128; off > 0; off >>= 1) {
    if (t < off) red[t] += red[t + off];
    __syncthreads();
  }
  ws[WS_PS + t * Gsz + g] = w / red[0];
}

// ---------- K5: dist[b] = sum_g dbg*ps ----------
__global__ __launch_bounds__(64) void k_dist(const float* __restrict__ ws,
                                             float* __restrict__ out) {
  int b = blockIdx.x, g = threadIdx.x;
  float v = ws[WS_PS + b * Gsz + g] * out[OUT_DBG + b * Gsz + g];
#pragma unroll
  for (int off = 32; off > 0; off >>= 1) v += __shfl_down(v, off);
  if (g == 0) out[OUT_DIST + b] = v;
}

// ---------- K7: fused states + quantised_{mu,sig} ----------
// per block: one x, one 64-wide d-tile. S[g][e][64d] built from softs*on_states,
// then out[x,b,dtile] = sum_g ps[b,g]*S[g][e][d] for all 256 b (2 passes of 128).
__global__ __launch_bounds__(256) void k_quant(const float* __restrict__ on,
                                               const float* __restrict__ ws,
                                               float* __restrict__ out) {
  __shared__ float S[64 * 128];  // [g][e][64]: g*128 + e*64 + d   (32 KB)
  __shared__ float P[128 * 64];  // pass ps [b_l][g] (32 KB); first 512 = softs stage
  int x = blockIdx.x >> 3, dblk = blockIdx.x & 7;
  int dBase = dblk << 6;
  int t = threadIdx.x, tx = t & 15, ty = t >> 4;

  // softs for this x into P[0..511]
  P[t] = ws[WS_SOFTS + x * 512 + t];
  P[t + 256] = ws[WS_SOFTS + x * 512 + 256 + t];
  __syncthreads();

  // build S tile
#pragma unroll
  for (int it = 0; it < 16; ++it) {
    int idx = t + (it << 8);  // 0..4095
    int g = idx >> 6, d = idx & 63;
    float a0 = 0.f, a1 = 0.f;
    const float* op = on + (size_t)(g * 8) * DDsz + (size_t)(dBase + d) * 2;
#pragma unroll
    for (int n = 0; n < 8; ++n) {
      float sw = P[g * 8 + n];
      float2 a = *(const float2*)(op + n * DDsz);
      a0 += sw * a.x;
      a1 += sw * a.y;
    }
    S[g * 128 + d] = a0;
    S[g * 128 + 64 + d] = a1;
  }
  __syncthreads();

#pragma unroll 1
  for (int pass = 0; pass < 2; ++pass) {
    // stage ps chunk [128 b][64 g] — straight copy, coalesced
#pragma unroll
    for (int r = 0; r < 32; ++r)
      P[t + (r << 8)] = ws[WS_PS + (pass << 13) + t + (r << 8)];
    __syncthreads();

    float ac0[8][4], ac1[8][4];
#pragma unroll
    for (int i = 0; i < 8; ++i)
#pragma unroll
      for (int j = 0; j < 4; ++j) { ac0[i][j] = 0.f; ac1[i][j] = 0.f; }

    for (int g = 0; g < 64; ++g) {
      float4 s0 = *(const float4*)&S[g * 128 + (tx << 2)];
      float4 s1 = *(const float4*)&S[g * 128 + 64 + (tx << 2)];
#pragma unroll
      for (int i = 0; i < 8; ++i) {
        float pv = P[(ty * 8 + i) * 64 + g];
        ac0[i][0] += pv * s0.x; ac0[i][1] += pv * s0.y;
        ac0[i][2] += pv * s0.z; ac0[i][3] += pv * s0.w;
        ac1[i][0] += pv * s1.x; ac1[i][1] += pv * s1.y;
        ac1[i][2] += pv * s1.z; ac1[i][3] += pv * s1.w;
      }
    }

#pragma unroll
    for (int i = 0; i < 8; ++i) {
      int b = (pass << 7) + ty * 8 + i;
      size_t base = ((size_t)x * Bsz + b) * Dsz + dBase + (tx << 2);
      float4 o0 = make_float4(ac0[i][0], ac0[i][1], ac0[i][2], ac0[i][3]);
      float4 o1 = make_float4(ac1[i][0], ac1[i][1], ac1[i][2], ac1[i][3]);
      *(float4*)&out[OUT_QMU + base] = o0;
      *(float4*)&out[OUT_QSIG + base] = o1;
    }
    __syncthreads();
  }
}

extern "C" void kernel_launch(void* const* d_in, const int* in_sizes, int n_in,
                              void* d_out, int out_size, void* d_ws, size_t ws_size,
                              hipStream_t stream) {
  const float* mu = (const float*)d_in[0];
  const float* ls = (const float*)d_in[1];
  const float* on = (const float*)d_in[2];
  float* out = (float*)d_out;
  float* ws = (float*)d_ws;

  k_prep_b<<<dim3(Bsz), dim3(256), 0, stream>>>(mu, ls, ws);
  k_prep_c<<<dim3(Ksz), dim3(256), 0, stream>>>(on, ws);
  k_dkb<<<dim3(128), dim3(256), 0, stream>>>(on, ws);
  k_gsm<<<dim3(64), dim3(256), 0, stream>>>(ws, out);
  k_ps<<<dim3(Gsz), dim3(256), 0, stream>>>(out, ws);
  k_dist<<<dim3(Bsz), dim3(64), 0, stream>>>(ws, out);
  k_quant<<<dim3(2048), dim3(256), 0, stream>>>(on, ws, out);
}

// Round 2
// 81.597 us; speedup vs baseline: 1.9231x; 1.9231x over previous
//
#include <hip/hip_runtime.h>
#include <cstddef>
#include <cstdint>

typedef short bf16x8 __attribute__((ext_vector_type(8)));
typedef float f32x4 __attribute__((ext_vector_type(4)));

#define Bsz 256
#define Dsz 512
#define Gsz 64
#define Ksz 512

// ws float offsets
#define WS_DFLAT 0         // [512][256] f32
#define WS_SOFTS 131072    // [256][512] f32 (b-major, flat-k)
#define WS_PS    262144    // [256][64] f32
#define WS_BNORM 278528    // [256]
#define WS_CNORM 278784    // [512]
#define WS_PSB   279296    // [256][64] bf16 (16384 ushorts = 8192 floats)
#define WS_ONB   287488    // 2 planes [512][512] bf16
#define WS_ZB    549632    // 2 planes [256][512] bf16

#define ONB_STRIDE 262144  // ushorts per plane
#define ZB_STRIDE  131072  // ushorts per plane

// out float offsets
#define OUT_QMU  0
#define OUT_QSIG 33554432
#define OUT_DBG  67108864
#define OUT_DIST 67125248

__device__ __forceinline__ unsigned short f2bf(float f) {
  unsigned int u = __float_as_uint(f);
  u = (u + 0x7FFFu + ((u >> 16) & 1u)) >> 16;
  return (unsigned short)u;
}
__device__ __forceinline__ float bf2f(unsigned short h) {
  return __uint_as_float(((unsigned int)h) << 16);
}

// ---------- K1: prep. blocks 0..511: on-row k (cnorm + onb planes).
//                blocks 512..767: batch-row b (bnorm + zb planes). ----------
__global__ __launch_bounds__(256) void k_prep(const float* __restrict__ mu,
                                              const float* __restrict__ ls,
                                              const float* __restrict__ on,
                                              float* __restrict__ ws) {
  int t = threadIdx.x;
  __shared__ float red[256];
  if (blockIdx.x < 512) {
    int k = blockIdx.x;
    float4 v = *(const float4*)(on + (size_t)k * 1024 + 4 * t);  // (d=2t,e0),(2t,e1),(2t+1,e0),(2t+1,e1)
    unsigned short* onb0 = (unsigned short*)(ws + WS_ONB);
    unsigned short* onb1 = onb0 + ONB_STRIDE;
    *(ushort2*)&onb0[(size_t)k * 512 + 2 * t] = make_ushort2(f2bf(v.x), f2bf(v.z));
    *(ushort2*)&onb1[(size_t)k * 512 + 2 * t] = make_ushort2(f2bf(v.y), f2bf(v.w));
    red[t] = v.x * v.x + v.y * v.y + v.z * v.z + v.w * v.w;
    __syncthreads();
    for (int off = 128; off > 0; off >>= 1) {
      if (t < off) red[t] += red[t + off];
      __syncthreads();
    }
    if (t == 0) ws[WS_CNORM + k] = red[0];
  } else {
    int b = blockIdx.x - 512;
    unsigned short* zb0 = (unsigned short*)(ws + WS_ZB);
    unsigned short* zb1 = zb0 + ZB_STRIDE;
    float part = 0.f;
    for (int d = t; d < Dsz; d += 256) {
      float m = mu[b * Dsz + d];
      float s = expf(ls[b * Dsz + d]);
      zb0[(size_t)b * 512 + d] = f2bf(m);
      zb1[(size_t)b * 512 + d] = f2bf(s);
      part += m * m + s * s;
    }
    red[t] = part;
    __syncthreads();
    for (int off = 128; off > 0; off >>= 1) {
      if (t < off) red[t] += red[t + off];
      __syncthreads();
    }
    if (t == 0) ws[WS_BNORM + b] = red[0];
  }
}

// ---------- K2: d_kb[k][b] = cnorm + bnorm - 2*dot via bf16 MFMA ----------
// grid 128 = kt(16) x bt(8); block tile 32k x 32b; wave w owns K-quarter.
__global__ __launch_bounds__(256) void k_dkb(float* __restrict__ ws) {
  __shared__ float pl[4][32][32];
  int t = threadIdx.x, l = t & 63, w = t >> 6;
  int lr = l & 15, lh = l >> 4;
  int kt = blockIdx.x >> 3, bt = blockIdx.x & 7;
  int k0 = kt * 32, b0 = bt * 32;
  const unsigned short* Ap =
      (const unsigned short*)(ws + WS_ONB) + (size_t)(w >> 1) * ONB_STRIDE + (size_t)k0 * 512;
  const unsigned short* Bp =
      (const unsigned short*)(ws + WS_ZB) + (size_t)(w >> 1) * ZB_STRIDE + (size_t)b0 * 512;
  int dbase = (w & 1) * 256;

  f32x4 acc[2][2];
#pragma unroll
  for (int i = 0; i < 2; ++i)
#pragma unroll
    for (int j = 0; j < 2; ++j) {
      acc[i][j][0] = 0.f; acc[i][j][1] = 0.f; acc[i][j][2] = 0.f; acc[i][j][3] = 0.f;
    }

#pragma unroll
  for (int kk = 0; kk < 8; ++kk) {
    int dl = dbase + kk * 32 + lh * 8;
    bf16x8 a0 = *(const bf16x8*)(Ap + (size_t)lr * 512 + dl);
    bf16x8 a1 = *(const bf16x8*)(Ap + (size_t)(lr + 16) * 512 + dl);
    bf16x8 q0 = *(const bf16x8*)(Bp + (size_t)lr * 512 + dl);
    bf16x8 q1 = *(const bf16x8*)(Bp + (size_t)(lr + 16) * 512 + dl);
    acc[0][0] = __builtin_amdgcn_mfma_f32_16x16x32_bf16(a0, q0, acc[0][0], 0, 0, 0);
    acc[0][1] = __builtin_amdgcn_mfma_f32_16x16x32_bf16(a0, q1, acc[0][1], 0, 0, 0);
    acc[1][0] = __builtin_amdgcn_mfma_f32_16x16x32_bf16(a1, q0, acc[1][0], 0, 0, 0);
    acc[1][1] = __builtin_amdgcn_mfma_f32_16x16x32_bf16(a1, q1, acc[1][1], 0, 0, 0);
  }

#pragma unroll
  for (int i = 0; i < 2; ++i)
#pragma unroll
    for (int j = 0; j < 2; ++j)
#pragma unroll
      for (int r = 0; r < 4; ++r)
        pl[w][i * 16 + lh * 4 + r][j * 16 + lr] = acc[i][j][r];
  __syncthreads();

  int kl = t >> 3, bl = (t & 7) * 4;
  float cn = ws[WS_CNORM + k0 + kl];
  f32x4 o;
#pragma unroll
  for (int q = 0; q < 4; ++q) {
    float s = pl[0][kl][bl + q] + pl[1][kl][bl + q] + pl[2][kl][bl + q] + pl[3][kl][bl + q];
    o[q] = cn + ws[WS_BNORM + b0 + bl + q] - 2.f * s;
  }
  *(f32x4*)&ws[WS_DFLAT + (size_t)(k0 + kl) * 256 + b0 + bl] = o;
}

// ---------- K3: fused group-softmax (scrambled) + ps softmax over batch ----------
// grid 64 = g; thread t = b.
__global__ __launch_bounds__(256) void k_sm(float* __restrict__ ws,
                                            float* __restrict__ out) {
  int g = blockIdx.x, t = threadIdx.x;
  const float* df = ws + WS_DFLAT;
  int k = 2 * t + (g >> 5);
  int col = (g & 31) << 3;
  const float* p = df + (size_t)k * 256 + col;
  float4 v0 = *(const float4*)p;
  float4 v1 = *(const float4*)(p + 4);
  float d[8] = {v0.x, v0.y, v0.z, v0.w, v1.x, v1.y, v1.z, v1.w};
  float m = d[0];
#pragma unroll
  for (int n = 1; n < 8; ++n) m = fminf(m, d[n]);
  float wv[8], s = 0.f, wd = 0.f;
#pragma unroll
  for (int n = 0; n < 8; ++n) {
    wv[n] = expf(m - d[n]);
    s += wv[n];
    wd += wv[n] * d[n];
  }
  float inv = 1.f / s;
  float* so = ws + WS_SOFTS + (size_t)t * 512 + g * 8;
  *(float4*)so = make_float4(wv[0] * inv, wv[1] * inv, wv[2] * inv, wv[3] * inv);
  *(float4*)(so + 4) = make_float4(wv[4] * inv, wv[5] * inv, wv[6] * inv, wv[7] * inv);
  float dbg = wd * inv;
  out[OUT_DBG + t * 64 + g] = dbg;

  __shared__ float red[256];
  red[t] = dbg;
  __syncthreads();
  for (int off = 128; off > 0; off >>= 1) {
    if (t < off) red[t] = fminf(red[t], red[t + off]);
    __syncthreads();
  }
  float mm = red[0];
  __syncthreads();
  float wp = expf(mm - dbg);
  red[t] = wp;
  __syncthreads();
  for (int off = 128; off > 0; off >>= 1) {
    if (t < off) red[t] += red[t + off];
    __syncthreads();
  }
  float psv = wp / red[0];
  ws[WS_PS + t * 64 + g] = psv;
  ((unsigned short*)(ws + WS_PSB))[t * 64 + g] = f2bf(psv);
}

// ---------- K4: dist[b] = sum_g dbg*ps ----------
__global__ __launch_bounds__(64) void k_dist(const float* __restrict__ ws,
                                             float* __restrict__ out) {
  int b = blockIdx.x, g = threadIdx.x;
  float v = ws[WS_PS + b * 64 + g] * out[OUT_DBG + b * 64 + g];
#pragma unroll
  for (int off = 32; off > 0; off >>= 1) v += __shfl_down(v, off);
  if (g == 0) out[OUT_DIST + b] = v;
}

// ---------- K5: quantised_{mu,sig} via bf16 MFMA ----------
// grid 2048 = x(256) x dt(8); block: 256 b x 64 d x 2 planes.
// C'[d][b] = sum_g S_T[d][g] * ps[b][g]; A=S_T, B=ps (both [row][64g] in LDS, XOR-swizzled).
__global__ __launch_bounds__(256) void k_quant(const float* __restrict__ ws,
                                               float* __restrict__ out) {
  __shared__ __align__(16) unsigned short psl[16384];  // [b][g] swz, 32 KB
  __shared__ __align__(16) unsigned short st[4096];    // [d][g] swz, 8 KB
  __shared__ float sxl[512];
  int x = blockIdx.x >> 3, dt = blockIdx.x & 7;
  int dBase = dt * 64;
  int t = threadIdx.x, l = t & 63, w = t >> 6;
  int lr = l & 15, lh = l >> 4;

  const unsigned short* psb = (const unsigned short*)(ws + WS_PSB);
#pragma unroll
  for (int c = 0; c < 8; ++c) {
    int cc = t + c * 256;           // 0..2047 chunks of 8 ushorts
    int b = cc >> 3, gw8 = (cc & 7) * 8;
    bf16x8 v = *(const bf16x8*)(psb + (size_t)b * 64 + gw8);
    *(bf16x8*)&psl[(b * 64 + gw8) ^ ((b & 7) << 3)] = v;
  }
  sxl[t] = ws[WS_SOFTS + (size_t)x * 512 + t];
  sxl[t + 256] = ws[WS_SOFTS + (size_t)x * 512 + 256 + t];
  __syncthreads();

  // B frags (ps) — same for both planes
  bf16x8 bn[4][2];
#pragma unroll
  for (int j = 0; j < 4; ++j)
#pragma unroll
    for (int kk = 0; kk < 2; ++kk) {
      int b = w * 64 + j * 16 + lr;
      bn[j][kk] = *(const bf16x8*)&psl[(b * 64 + kk * 32 + lh * 8) ^ ((b & 7) << 3)];
    }

  const unsigned short* onb = (const unsigned short*)(ws + WS_ONB);
#pragma unroll 1
  for (int e = 0; e < 2; ++e) {
    __syncthreads();
    // build S_T[d][g] for this plane: thread owns 4 d x 16 g (x4 passes)
    {
      const unsigned short* obp = onb + (size_t)e * ONB_STRIDE + dBase + (t & 15) * 4;
      int gq = t >> 4;
      int dl2 = (t & 15) * 4;
#pragma unroll
      for (int go = 0; go < 4; ++go) {
        int g = go * 16 + gq;
        float a0 = 0.f, a1 = 0.f, a2 = 0.f, a3 = 0.f;
        const unsigned short* rp = obp + (size_t)(g * 8) * 512;
#pragma unroll
        for (int n = 0; n < 8; ++n) {
          ushort4 vv = *(const ushort4*)(rp + (size_t)n * 512);
          float swv = sxl[g * 8 + n];
          a0 += swv * bf2f(vv.x);
          a1 += swv * bf2f(vv.y);
          a2 += swv * bf2f(vv.z);
          a3 += swv * bf2f(vv.w);
        }
        st[((dl2 + 0) * 64 + g) ^ (((dl2 + 0) & 7) << 3)] = f2bf(a0);
        st[((dl2 + 1) * 64 + g) ^ (((dl2 + 1) & 7) << 3)] = f2bf(a1);
        st[((dl2 + 2) * 64 + g) ^ (((dl2 + 2) & 7) << 3)] = f2bf(a2);
        st[((dl2 + 3) * 64 + g) ^ (((dl2 + 3) & 7) << 3)] = f2bf(a3);
      }
    }
    __syncthreads();

    bf16x8 am[4][2];
#pragma unroll
    for (int i = 0; i < 4; ++i)
#pragma unroll
      for (int kk = 0; kk < 2; ++kk) {
        int d = i * 16 + lr;
        am[i][kk] = *(const bf16x8*)&st[(d * 64 + kk * 32 + lh * 8) ^ ((d & 7) << 3)];
      }

    f32x4 acc[4][4];
#pragma unroll
    for (int i = 0; i < 4; ++i)
#pragma unroll
      for (int j = 0; j < 4; ++j) {
        acc[i][j][0] = 0.f; acc[i][j][1] = 0.f; acc[i][j][2] = 0.f; acc[i][j][3] = 0.f;
      }
#pragma unroll
    for (int kk = 0; kk < 2; ++kk)
#pragma unroll
      for (int i = 0; i < 4; ++i)
#pragma unroll
        for (int j = 0; j < 4; ++j)
          acc[i][j] = __builtin_amdgcn_mfma_f32_16x16x32_bf16(am[i][kk], bn[j][kk], acc[i][j], 0, 0, 0);

    float* op = out + (e ? (size_t)OUT_QSIG : (size_t)OUT_QMU) + (size_t)x * (256 * 512);
#pragma unroll
    for (int i = 0; i < 4; ++i)
#pragma unroll
      for (int j = 0; j < 4; ++j) {
        int b = w * 64 + j * 16 + lr;
        int d = dBase + i * 16 + lh * 4;
        *(f32x4*)&op[(size_t)b * 512 + d] = acc[i][j];
      }
  }
}

extern "C" void kernel_launch(void* const* d_in, const int* in_sizes, int n_in,
                              void* d_out, int out_size, void* d_ws, size_t ws_size,
                              hipStream_t stream) {
  (void)in_sizes; (void)n_in; (void)out_size; (void)ws_size;
  const float* mu = (const float*)d_in[0];
  const float* ls = (const float*)d_in[1];
  const float* on = (const float*)d_in[2];
  float* out = (float*)d_out;
  float* ws = (float*)d_ws;

  k_prep<<<dim3(768), dim3(256), 0, stream>>>(mu, ls, on, ws);
  k_dkb<<<dim3(128), dim3(256), 0, stream>>>(ws);
  k_sm<<<dim3(64), dim3(256), 0, stream>>>(ws, out);
  k_dist<<<dim3(256), dim3(64), 0, stream>>>(ws, out);
  k_quant<<<dim3(2048), dim3(256), 0, stream>>>(ws, out);
}